// Round 8
// baseline (170.495 us; speedup 1.0000x reference)
//
#include <hip/hip_runtime.h>
#include <hip/hip_bf16.h>
#include <stdint.h>

// ---------------------------------------------------------------------------
// VectorAttentionLayerV3: fused bf16-MFMA implementation for MI355X (gfx950)
// B=2, N=16384, M=16, C=64, H=64
//
// Math (BN folded into conv1, W1 folded through Q/K projections):
//   h   = center@Aq^T - nbr@Ak^T + pos@A1^T + b1      (Ak stored pre-negated)
//   a2  = relu(h) @ W2^T
//   w   = softmax_m(a2)
//   out = sum_m w * (nbr@Wv^T + pos)
//
// R1: GEMM1 transposed (weights as MFMA-A) -> h^T lands in A-frag layout for
//     GEMM2; no LDS round-trip in the main loop.
// R6: pinned pipeline: ISSUE(n+1); sched_barrier(0); compute(n). pos-for-
//     output used as V-MFMA C-init.
// R7: pinned ILP x high residency: 512-thr blocks, __launch_bounds__(512,4)
//     (VGPR cap 128 > natural ~110 -> no spill, 4 waves/SIMD target);
//     rq loads moved compute-local (slims double-buffer to 96 VGPR);
//     softmax div via v_rcp.
// ---------------------------------------------------------------------------

#define NN 16384

typedef float f32x4 __attribute__((ext_vector_type(4)));
typedef short s16x8 __attribute__((ext_vector_type(8)));
typedef int   i32x4 __attribute__((ext_vector_type(4)));

// hot-path pack: hardware cvt_pk (RNE), 2 floats -> 1 dword of 2 bf16
__device__ __forceinline__ uint32_t pk2(float a, float b) {
  float2 f; f.x = a; f.y = b;
  __hip_bfloat162 h = __float22bfloat162_rn(f);
  uint32_t u;
  __builtin_memcpy(&u, &h, 4);
  return u;
}

__device__ __forceinline__ f32x4 mma16(i32x4 a, i32x4 b, f32x4 c) {
  return __builtin_amdgcn_mfma_f32_16x16x32_bf16(
      __builtin_bit_cast(s16x8, a), __builtin_bit_cast(s16x8, b), c, 0, 0, 0);
}

// pack two f32x4 halves (k 0..3 / k 16..19 pattern) into one bf16 fragment
__device__ __forceinline__ i32x4 packfrag(f32x4 f0, f32x4 f1) {
  i32x4 r;
  r.x = pk2(f0.x, f0.y); r.y = pk2(f0.z, f0.w);
  r.z = pk2(f1.x, f1.y); r.w = pk2(f1.z, f1.w);
  return r;
}

// ---------------- weight prepass: combine, scale, pack to frag layout ------
// Packed layout (works as A-frag via rows or B-frag via cols — same mapping):
// wp[((mat*8 + kt*4 + ct)*64 + lane)*8 + e], where index16 = 16*ct + (lane&15),
// k = kt*32 + (e>=4)*16 + 4*(lane>>4) + (e&3)
__device__ __forceinline__ void wstore(uint16_t* wp, int mat, int j, int k, float v) {
  int ct = j >> 4, jl = j & 15;
  int kt = k >> 5, r = k & 31;
  int kh = r >> 4, rr = r & 15;
  int gg = rr >> 2, e2 = rr & 3;
  int lanei = jl + (gg << 4);
  int e = kh * 4 + e2;
  uint32_t u = __builtin_bit_cast(uint32_t, v);
  u += 0x7fffu + ((u >> 16) & 1u);
  wp[((mat * 8 + kt * 4 + ct) * 64 + lanei) * 8 + e] = (uint16_t)(u >> 16);
}

__global__ void prep_weights(const float* __restrict__ Wq, const float* __restrict__ Wkv,
                             const float* __restrict__ W1, const float* __restrict__ gam,
                             const float* __restrict__ bet, const float* __restrict__ mu,
                             const float* __restrict__ var, const float* __restrict__ W2,
                             uint16_t* __restrict__ wp, float* __restrict__ b1) {
  int j = blockIdx.x * 16 + (threadIdx.x >> 4);   // out index 0..63
  int q = threadIdx.x & 15;
  float gp = gam[j] * rsqrtf(var[j] + 1e-5f);
  if (q == 0) b1[j] = bet[j] - gp * mu[j];
  for (int k = q * 4; k < q * 4 + 4; ++k) {
    float aq = 0.f, ak = 0.f;
    for (int c = 0; c < 64; ++c) {
      float w1 = W1[j * 64 + c];
      aq += w1 * Wq[c * 64 + k];     // (W1·Wq)[j][k]
      ak += w1 * Wkv[c * 64 + k];    // (W1·Wk)[j][k]
    }
    wstore(wp, 0, j, k, gp * aq);                 // Aq   (A-frag rows=ch)
    wstore(wp, 1, j, k, -gp * ak);                // -Ak  (pre-negated)
    wstore(wp, 2, j, k, gp * W1[j * 64 + k]);     // A1
    wstore(wp, 3, j, k, Wkv[(64 + j) * 64 + k]);  // Wv   (B-frag cols=cv)
    wstore(wp, 4, j, k, W2[j * 64 + k]);          // W2   (B-frag cols=c2)
  }
}

// ---------------- main fused kernel ----------------------------------------
#define W_LDS_ELEMS (5 * 4096)   // 40960 B; 8 waves share one copy

__device__ __forceinline__ i32x4 bfragld(const uint16_t* wlds, int mat, int kt, int ct, int lane) {
  return *(const i32x4*)(wlds + ((mat * 8 + kt * 4 + ct) * 64 + lane) * 8);
}

__global__ __launch_bounds__(512, 4) void vattn_main(
    const float* __restrict__ center, const float* __restrict__ nbr,
    const float* __restrict__ pos, const uint16_t* __restrict__ wp,
    const float* __restrict__ b1, float* __restrict__ out) {
  __shared__ uint16_t wlds[W_LDS_ELEMS];
  const int tid = threadIdx.x;
  {
    const i32x4* src = (const i32x4*)wp;
    i32x4* dst = (i32x4*)wlds;
#pragma unroll
    for (int i = 0; i < 5; ++i) dst[tid + 512 * i] = src[tid + 512 * i];
  }
  __syncthreads();

  const int w = tid >> 6;            // 0..7
  const int lane = tid & 63;
  const int l15 = lane & 15;
  const int g = lane >> 4;
  const int blk = blockIdx.x;
  const int b = blk >> 9;
  const int n0 = (blk & 511) << 5;   // 32 n per block
  const long nbase = (long)b * NN + n0 + (w << 2);   // this wave's first n

  // BN bias as accumulator init: lane holds channels ct*16 + 4g + r
  f32x4 binit[4];
#pragma unroll
  for (int ct = 0; ct < 4; ++ct)
#pragma unroll
    for (int r = 0; r < 4; ++r) binit[ct][r] = b1[ct * 16 + 4 * g + r];

  // double-buffered raw prefetch: nbr, pos, center fragments (48 dw/buffer)
  f32x4 rn[2][4], rp[2][4], rc[2][4];

#define ISSUE(BUF, RT) do {                                                    \
    const long nr_ = nbase + (RT);                                             \
    const float* nrp_ = nbr + ((nr_ * 16 + l15) * 64) + g * 4;                 \
    const float* prp_ = pos + ((nr_ * 16 + l15) * 64) + g * 4;                 \
    const float* crp_ = center + nr_ * 64 + g * 4;                             \
    rn[BUF][0] = *(const f32x4*)nrp_;        rn[BUF][1] = *(const f32x4*)(nrp_ + 16); \
    rn[BUF][2] = *(const f32x4*)(nrp_ + 32); rn[BUF][3] = *(const f32x4*)(nrp_ + 48); \
    rp[BUF][0] = *(const f32x4*)prp_;        rp[BUF][1] = *(const f32x4*)(prp_ + 16); \
    rp[BUF][2] = *(const f32x4*)(prp_ + 32); rp[BUF][3] = *(const f32x4*)(prp_ + 48); \
    rc[BUF][0] = *(const f32x4*)crp_;        rc[BUF][1] = *(const f32x4*)(crp_ + 16); \
    rc[BUF][2] = *(const f32x4*)(crp_ + 32); rc[BUF][3] = *(const f32x4*)(crp_ + 48); \
    __builtin_amdgcn_sched_barrier(0);                                         \
  } while (0)

  ISSUE(0, 0);

#pragma unroll
  for (int rt = 0; rt < 4; ++rt) {
    if (rt < 3) ISSUE((rt + 1) & 1, rt + 1);   // loads pinned before compute(rt)
    const int buf = rt & 1;
    const long nrow = nbase + rt;

    // rq: pos in C/D layout for the V accumulator init. Same 4KB row-block as
    // rp(rt) -> L1-hot; issued here so GEMM1 covers its latency.
    const float* pr = pos + nrow * 1024;
    f32x4 rq[4];
#pragma unroll
    for (int ct = 0; ct < 4; ++ct)
#pragma unroll
      for (int r = 0; r < 4; ++r)
        rq[ct][r] = pr[(4 * g + r) * 64 + ct * 16 + l15];

    // pack current buffer to bf16 fragments (MFMA-B: col=m=l15; center bcast)
    i32x4 na0 = packfrag(rn[buf][0], rn[buf][1]);
    i32x4 na1 = packfrag(rn[buf][2], rn[buf][3]);
    i32x4 pa0 = packfrag(rp[buf][0], rp[buf][1]);
    i32x4 pa1 = packfrag(rp[buf][2], rp[buf][3]);
    i32x4 ca0 = packfrag(rc[buf][0], rc[buf][1]);
    i32x4 ca1 = packfrag(rc[buf][2], rc[buf][3]);

    // GEMM1 (transposed): h^T[ch][m], weights as A, data as B. 24 MFMAs.
    f32x4 h[4];
#pragma unroll
    for (int ct = 0; ct < 4; ++ct) {
      h[ct] = binit[ct];
      h[ct] = mma16(bfragld(wlds, 0, 0, ct, lane), ca0, h[ct]);  // Aq · center
      h[ct] = mma16(bfragld(wlds, 0, 1, ct, lane), ca1, h[ct]);
      h[ct] = mma16(bfragld(wlds, 1, 0, ct, lane), na0, h[ct]);  // -Ak · nbr
      h[ct] = mma16(bfragld(wlds, 1, 1, ct, lane), na1, h[ct]);
      h[ct] = mma16(bfragld(wlds, 2, 0, ct, lane), pa0, h[ct]);  // A1 · pos
      h[ct] = mma16(bfragld(wlds, 2, 1, ct, lane), pa1, h[ct]);
    }

    // V GEMM (untransposed): vv[m][cv] = pos(C-init) + nbr@Wv^T. 8 MFMAs.
    f32x4 vv[4];
#pragma unroll
    for (int ct = 0; ct < 4; ++ct) {
      vv[ct] = rq[ct];                            // (V + pos): pos via C-init
      vv[ct] = mma16(na0, bfragld(wlds, 3, 0, ct, lane), vv[ct]);
      vv[ct] = mma16(na1, bfragld(wlds, 3, 1, ct, lane), vv[ct]);
    }

    // relu + repack: h^T C/D layout IS the A-frag layout for GEMM2
    i32x4 ha0, ha1;
    {
      f32x4 r0, r1, r2, r3;
#pragma unroll
      for (int r = 0; r < 4; ++r) {
        r0[r] = fmaxf(h[0][r], 0.f); r1[r] = fmaxf(h[1][r], 0.f);
        r2[r] = fmaxf(h[2][r], 0.f); r3[r] = fmaxf(h[3][r], 0.f);
      }
      ha0 = packfrag(r0, r1);   // k(ch) 0..31
      ha1 = packfrag(r2, r3);   // k(ch) 32..63
    }

    // GEMM2 (untransposed): a2[m][c2] = relu(h) @ W2^T. 8 MFMAs.
    f32x4 a2[4];
#pragma unroll
    for (int ct = 0; ct < 4; ++ct) {
      a2[ct] = (f32x4){0.f, 0.f, 0.f, 0.f};
      a2[ct] = mma16(ha0, bfragld(wlds, 4, 0, ct, lane), a2[ct]);
      a2[ct] = mma16(ha1, bfragld(wlds, 4, 1, ct, lane), a2[ct]);
    }

    // softmax over m + weighted sum — all in-register (no global loads)
    float ov[4];
#pragma unroll
    for (int ct = 0; ct < 4; ++ct) {
      f32x4 s = a2[ct];
      float mx = fmaxf(fmaxf(s.x, s.y), fmaxf(s.z, s.w));
      mx = fmaxf(mx, __shfl_xor(mx, 16, 64));
      mx = fmaxf(mx, __shfl_xor(mx, 32, 64));
      float e0 = __expf(s.x - mx), e1 = __expf(s.y - mx);
      float e2 = __expf(s.z - mx), e3 = __expf(s.w - mx);
      float sm = e0 + e1 + e2 + e3;
      sm += __shfl_xor(sm, 16, 64);
      sm += __shfl_xor(sm, 32, 64);
      float ps = e0 * vv[ct].x + e1 * vv[ct].y + e2 * vv[ct].z + e3 * vv[ct].w;
      ps += __shfl_xor(ps, 16, 64);
      ps += __shfl_xor(ps, 32, 64);
      ov[ct] = ps * __builtin_amdgcn_rcpf(sm);   // |rel err| ~2^-22, ok for bf16 budget
    }
    // lane = l15 + 16g stores channel c2 = 16*g + l15 = lane (coalesced)
    float val = (g == 0) ? ov[0] : (g == 1) ? ov[1] : (g == 2) ? ov[2] : ov[3];
    out[nrow * 64 + lane] = val;
  }
#undef ISSUE
}

// ---------------------------------------------------------------------------
extern "C" void kernel_launch(void* const* d_in, const int* in_sizes, int n_in,
                              void* d_out, int out_size, void* d_ws, size_t ws_size,
                              hipStream_t stream) {
  const float* center = (const float*)d_in[0];
  const float* nbr    = (const float*)d_in[1];
  const float* pos    = (const float*)d_in[2];
  const float* Wq     = (const float*)d_in[3];
  const float* Wkv    = (const float*)d_in[4];
  const float* W1     = (const float*)d_in[5];
  const float* gam    = (const float*)d_in[6];
  const float* bet    = (const float*)d_in[7];
  const float* mu     = (const float*)d_in[8];
  const float* var    = (const float*)d_in[9];
  const float* W2     = (const float*)d_in[10];
  uint16_t* wp = (uint16_t*)d_ws;
  float* b1 = (float*)((char*)d_ws + 5 * 4096 * 2);
  prep_weights<<<4, 256, 0, stream>>>(Wq, Wkv, W1, gam, bet, mu, var, W2, wp, b1);
  vattn_main<<<1024, 512, 0, stream>>>(center, nbr, pos, wp, b1, (float*)d_out);
}

// Round 9
// 101.678 us; speedup vs baseline: 1.6768x; 1.6768x over previous
//
#include <hip/hip_runtime.h>
#include <hip/hip_bf16.h>
#include <stdint.h>

// ---------------------------------------------------------------------------
// VectorAttentionLayerV3: fused bf16-MFMA implementation for MI355X (gfx950)
// B=2, N=16384, M=16, C=64, H=64
//
// Math (BN folded into conv1, W1 folded through Q/K projections):
//   h   = center@Aq^T - nbr@Ak^T + pos@A1^T + b1      (Ak stored pre-negated)
//   a2  = relu(h) @ W2^T
//   w   = softmax_m(a2)
//   out = sum_m w * (nbr@Wv^T + pos)
//
// R1: GEMM1 transposed (weights as MFMA-A) -> h^T lands in A-frag layout for
//     GEMM2; no LDS round-trip in the main loop.
// R6: pinned pipeline: ISSUE(n+1); sched_barrier(0); compute(n); pos-for-
//     output as V-MFMA C-init.
// R7 lesson: 512-thr blocks' launch_bounds cap = 256/arg -> spill; unusable.
// R8: residency fixes at constant pipeline: LDS 40960->32768 (W2 frags in
//     registers; kills the razor-edge 4x40960=160KiB alloc), grid 1024 with
//     32 n/block (8-deep per-wave pipeline, half the staging events).
// ---------------------------------------------------------------------------

#define NN 16384

typedef float f32x4 __attribute__((ext_vector_type(4)));
typedef short s16x8 __attribute__((ext_vector_type(8)));
typedef int   i32x4 __attribute__((ext_vector_type(4)));

// hot-path pack: hardware cvt_pk (RNE), 2 floats -> 1 dword of 2 bf16
__device__ __forceinline__ uint32_t pk2(float a, float b) {
  float2 f; f.x = a; f.y = b;
  __hip_bfloat162 h = __float22bfloat162_rn(f);
  uint32_t u;
  __builtin_memcpy(&u, &h, 4);
  return u;
}

__device__ __forceinline__ f32x4 mma16(i32x4 a, i32x4 b, f32x4 c) {
  return __builtin_amdgcn_mfma_f32_16x16x32_bf16(
      __builtin_bit_cast(s16x8, a), __builtin_bit_cast(s16x8, b), c, 0, 0, 0);
}

// pack two f32x4 halves (k 0..3 / k 16..19 pattern) into one bf16 fragment
__device__ __forceinline__ i32x4 packfrag(f32x4 f0, f32x4 f1) {
  i32x4 r;
  r.x = pk2(f0.x, f0.y); r.y = pk2(f0.z, f0.w);
  r.z = pk2(f1.x, f1.y); r.w = pk2(f1.z, f1.w);
  return r;
}

// ---------------- weight prepass: combine, scale, pack to frag layout ------
// Packed layout (works as A-frag via rows or B-frag via cols — same mapping):
// wp[((mat*8 + kt*4 + ct)*64 + lane)*8 + e], where index16 = 16*ct + (lane&15),
// k = kt*32 + (e>=4)*16 + 4*(lane>>4) + (e&3)
__device__ __forceinline__ void wstore(uint16_t* wp, int mat, int j, int k, float v) {
  int ct = j >> 4, jl = j & 15;
  int kt = k >> 5, r = k & 31;
  int kh = r >> 4, rr = r & 15;
  int gg = rr >> 2, e2 = rr & 3;
  int lanei = jl + (gg << 4);
  int e = kh * 4 + e2;
  uint32_t u = __builtin_bit_cast(uint32_t, v);
  u += 0x7fffu + ((u >> 16) & 1u);
  wp[((mat * 8 + kt * 4 + ct) * 64 + lanei) * 8 + e] = (uint16_t)(u >> 16);
}

__global__ void prep_weights(const float* __restrict__ Wq, const float* __restrict__ Wkv,
                             const float* __restrict__ W1, const float* __restrict__ gam,
                             const float* __restrict__ bet, const float* __restrict__ mu,
                             const float* __restrict__ var, const float* __restrict__ W2,
                             uint16_t* __restrict__ wp, float* __restrict__ b1) {
  int j = blockIdx.x * 16 + (threadIdx.x >> 4);   // out index 0..63
  int q = threadIdx.x & 15;
  float gp = gam[j] * rsqrtf(var[j] + 1e-5f);
  if (q == 0) b1[j] = bet[j] - gp * mu[j];
  for (int k = q * 4; k < q * 4 + 4; ++k) {
    float aq = 0.f, ak = 0.f;
    for (int c = 0; c < 64; ++c) {
      float w1 = W1[j * 64 + c];
      aq += w1 * Wq[c * 64 + k];     // (W1·Wq)[j][k]
      ak += w1 * Wkv[c * 64 + k];    // (W1·Wk)[j][k]
    }
    wstore(wp, 0, j, k, gp * aq);                 // Aq   (A-frag rows=ch)
    wstore(wp, 1, j, k, -gp * ak);                // -Ak  (pre-negated)
    wstore(wp, 2, j, k, gp * W1[j * 64 + k]);     // A1
    wstore(wp, 3, j, k, Wkv[(64 + j) * 64 + k]);  // Wv   (B-frag cols=cv)
    wstore(wp, 4, j, k, W2[j * 64 + k]);          // W2   (B-frag cols=c2; kept in regs)
  }
}

// ---------------- main fused kernel ----------------------------------------
#define W_LDS_ELEMS (4 * 4096)   // 32768 B: mats 0-3 only (W2 lives in regs)

__device__ __forceinline__ i32x4 bfragld(const uint16_t* wlds, int mat, int kt, int ct, int lane) {
  return *(const i32x4*)(wlds + ((mat * 8 + kt * 4 + ct) * 64 + lane) * 8);
}

__global__ __launch_bounds__(256, 2) void vattn_main(
    const float* __restrict__ center, const float* __restrict__ nbr,
    const float* __restrict__ pos, const uint16_t* __restrict__ wp,
    const float* __restrict__ b1, float* __restrict__ out) {
  __shared__ uint16_t wlds[W_LDS_ELEMS];
  const int tid = threadIdx.x;
  {
    const i32x4* src = (const i32x4*)wp;          // mats 0-3 = first 2048 i32x4
    i32x4* dst = (i32x4*)wlds;
#pragma unroll
    for (int i = 0; i < 8; ++i) dst[tid + 256 * i] = src[tid + 256 * i];
  }

  const int w = tid >> 6;            // 0..3
  const int lane = tid & 63;
  const int l15 = lane & 15;
  const int g = lane >> 4;

  // W2 fragments in registers (global read, L1/L2-hot: all waves same 8KB)
  i32x4 w2f[2][4];
#pragma unroll
  for (int kt = 0; kt < 2; ++kt)
#pragma unroll
    for (int ct = 0; ct < 4; ++ct)
      w2f[kt][ct] = *(const i32x4*)(wp + ((32 + kt * 4 + ct) * 64 + lane) * 8);

  // BN bias as accumulator init: lane holds channels ct*16 + 4g + r
  f32x4 binit[4];
#pragma unroll
  for (int ct = 0; ct < 4; ++ct)
#pragma unroll
    for (int r = 0; r < 4; ++r) binit[ct][r] = b1[ct * 16 + 4 * g + r];

  __syncthreads();

  const int blk = blockIdx.x;
  const int b = blk >> 9;
  const int n0 = (blk & 511) << 5;   // 32 n per block
  const long nbase = (long)b * NN + n0 + (w << 3);   // this wave's first n (8 n/wave)

  // double-buffered raw prefetch: nbr, pos, center fragments (48 dw/buffer)
  f32x4 rn[2][4], rp[2][4], rc[2][4];

#define ISSUE(BUF, RT) do {                                                    \
    const long nr_ = nbase + (RT);                                             \
    const float* nrp_ = nbr + ((nr_ * 16 + l15) * 64) + g * 4;                 \
    const float* prp_ = pos + ((nr_ * 16 + l15) * 64) + g * 4;                 \
    const float* crp_ = center + nr_ * 64 + g * 4;                             \
    rn[BUF][0] = *(const f32x4*)nrp_;        rn[BUF][1] = *(const f32x4*)(nrp_ + 16); \
    rn[BUF][2] = *(const f32x4*)(nrp_ + 32); rn[BUF][3] = *(const f32x4*)(nrp_ + 48); \
    rp[BUF][0] = *(const f32x4*)prp_;        rp[BUF][1] = *(const f32x4*)(prp_ + 16); \
    rp[BUF][2] = *(const f32x4*)(prp_ + 32); rp[BUF][3] = *(const f32x4*)(prp_ + 48); \
    rc[BUF][0] = *(const f32x4*)crp_;        rc[BUF][1] = *(const f32x4*)(crp_ + 16); \
    rc[BUF][2] = *(const f32x4*)(crp_ + 32); rc[BUF][3] = *(const f32x4*)(crp_ + 48); \
    __builtin_amdgcn_sched_barrier(0);                                         \
  } while (0)

  ISSUE(0, 0);

#pragma unroll
  for (int rt = 0; rt < 8; ++rt) {
    if (rt < 7) ISSUE((rt + 1) & 1, rt + 1);   // loads pinned before compute(rt)
    const int buf = rt & 1;
    const long nrow = nbase + rt;

    // rq: pos in C/D layout for the V accumulator init (same 4KB row-block as
    // rp(rt) -> L1-hot; GEMM1 covers its latency).
    const float* pr = pos + nrow * 1024;
    f32x4 rq[4];
#pragma unroll
    for (int ct = 0; ct < 4; ++ct)
#pragma unroll
      for (int r = 0; r < 4; ++r)
        rq[ct][r] = pr[(4 * g + r) * 64 + ct * 16 + l15];

    // pack current buffer to bf16 fragments (MFMA-B: col=m=l15; center bcast)
    i32x4 na0 = packfrag(rn[buf][0], rn[buf][1]);
    i32x4 na1 = packfrag(rn[buf][2], rn[buf][3]);
    i32x4 pa0 = packfrag(rp[buf][0], rp[buf][1]);
    i32x4 pa1 = packfrag(rp[buf][2], rp[buf][3]);
    i32x4 ca0 = packfrag(rc[buf][0], rc[buf][1]);
    i32x4 ca1 = packfrag(rc[buf][2], rc[buf][3]);

    // GEMM1 (transposed): h^T[ch][m], weights as A, data as B. 24 MFMAs.
    f32x4 h[4];
#pragma unroll
    for (int ct = 0; ct < 4; ++ct) {
      h[ct] = binit[ct];
      h[ct] = mma16(bfragld(wlds, 0, 0, ct, lane), ca0, h[ct]);  // Aq · center
      h[ct] = mma16(bfragld(wlds, 0, 1, ct, lane), ca1, h[ct]);
      h[ct] = mma16(bfragld(wlds, 1, 0, ct, lane), na0, h[ct]);  // -Ak · nbr
      h[ct] = mma16(bfragld(wlds, 1, 1, ct, lane), na1, h[ct]);
      h[ct] = mma16(bfragld(wlds, 2, 0, ct, lane), pa0, h[ct]);  // A1 · pos
      h[ct] = mma16(bfragld(wlds, 2, 1, ct, lane), pa1, h[ct]);
    }

    // V GEMM (untransposed): vv[m][cv] = pos(C-init) + nbr@Wv^T. 8 MFMAs.
    f32x4 vv[4];
#pragma unroll
    for (int ct = 0; ct < 4; ++ct) {
      vv[ct] = rq[ct];                            // (V + pos): pos via C-init
      vv[ct] = mma16(na0, bfragld(wlds, 3, 0, ct, lane), vv[ct]);
      vv[ct] = mma16(na1, bfragld(wlds, 3, 1, ct, lane), vv[ct]);
    }

    // relu + repack: h^T C/D layout IS the A-frag layout for GEMM2
    i32x4 ha0, ha1;
    {
      f32x4 r0, r1, r2, r3;
#pragma unroll
      for (int r = 0; r < 4; ++r) {
        r0[r] = fmaxf(h[0][r], 0.f); r1[r] = fmaxf(h[1][r], 0.f);
        r2[r] = fmaxf(h[2][r], 0.f); r3[r] = fmaxf(h[3][r], 0.f);
      }
      ha0 = packfrag(r0, r1);   // k(ch) 0..31
      ha1 = packfrag(r2, r3);   // k(ch) 32..63
    }

    // GEMM2 (untransposed): a2[m][c2] = relu(h) @ W2^T (regs). 8 MFMAs.
    f32x4 a2[4];
#pragma unroll
    for (int ct = 0; ct < 4; ++ct) {
      a2[ct] = (f32x4){0.f, 0.f, 0.f, 0.f};
      a2[ct] = mma16(ha0, w2f[0][ct], a2[ct]);
      a2[ct] = mma16(ha1, w2f[1][ct], a2[ct]);
    }

    // softmax over m + weighted sum — all in-register (no global loads)
    float ov[4];
#pragma unroll
    for (int ct = 0; ct < 4; ++ct) {
      f32x4 s = a2[ct];
      float mx = fmaxf(fmaxf(s.x, s.y), fmaxf(s.z, s.w));
      mx = fmaxf(mx, __shfl_xor(mx, 16, 64));
      mx = fmaxf(mx, __shfl_xor(mx, 32, 64));
      float e0 = __expf(s.x - mx), e1 = __expf(s.y - mx);
      float e2 = __expf(s.z - mx), e3 = __expf(s.w - mx);
      float sm = e0 + e1 + e2 + e3;
      sm += __shfl_xor(sm, 16, 64);
      sm += __shfl_xor(sm, 32, 64);
      float ps = e0 * vv[ct].x + e1 * vv[ct].y + e2 * vv[ct].z + e3 * vv[ct].w;
      ps += __shfl_xor(ps, 16, 64);
      ps += __shfl_xor(ps, 32, 64);
      ov[ct] = ps * __builtin_amdgcn_rcpf(sm);   // |rel err| ~2^-22, ok for bf16 budget
    }
    // lane = l15 + 16g stores channel c2 = 16*g + l15 = lane (coalesced)
    float val = (g == 0) ? ov[0] : (g == 1) ? ov[1] : (g == 2) ? ov[2] : ov[3];
    out[nrow * 64 + lane] = val;
  }
#undef ISSUE
}

// ---------------------------------------------------------------------------
extern "C" void kernel_launch(void* const* d_in, const int* in_sizes, int n_in,
                              void* d_out, int out_size, void* d_ws, size_t ws_size,
                              hipStream_t stream) {
  const float* center = (const float*)d_in[0];
  const float* nbr    = (const float*)d_in[1];
  const float* pos    = (const float*)d_in[2];
  const float* Wq     = (const float*)d_in[3];
  const float* Wkv    = (const float*)d_in[4];
  const float* W1     = (const float*)d_in[5];
  const float* gam    = (const float*)d_in[6];
  const float* bet    = (const float*)d_in[7];
  const float* mu     = (const float*)d_in[8];
  const float* var    = (const float*)d_in[9];
  const float* W2     = (const float*)d_in[10];
  uint16_t* wp = (uint16_t*)d_ws;
  float* b1 = (float*)((char*)d_ws + 5 * 4096 * 2);
  prep_weights<<<4, 256, 0, stream>>>(Wq, Wkv, W1, gam, bet, mu, var, W2, wp, b1);
  vattn_main<<<1024, 256, 0, stream>>>(center, nbr, pos, wp, b1, (float*)d_out);
}

// Round 10
// 97.585 us; speedup vs baseline: 1.7471x; 1.0419x over previous
//
#include <hip/hip_runtime.h>
#include <hip/hip_bf16.h>
#include <stdint.h>

// ---------------------------------------------------------------------------
// VectorAttentionLayerV3: fused bf16-MFMA implementation for MI355X (gfx950)
// B=2, N=16384, M=16, C=64, H=64
//
// Math (BN folded into conv1, W1 folded through Q/K projections):
//   h   = center@Aq^T - nbr@Ak^T + pos@A1^T + b1      (Ak stored pre-negated)
//   a2  = relu(h) @ W2^T
//   w   = softmax_m(a2)
//   out = sum_m w * (nbr@Wv^T + pos)
//
// R1-R8 lesson: VGPR-resident prefetch caps in-flight bytes at ~300B/wave ->
//   Little's law pins HBM at ~1.8 TB/s regardless of occupancy/ILP knobs.
// R9: global_load_lds ring staging. Per-wave private 2-slot ring in LDS
//   (nbr 4KB + pos 4KB per slot), 8 async width-16 DMA ops per slot, counted
//   s_waitcnt vmcnt(8) (never 0 mid-loop), no barriers in the main loop.
//   Weights: Aq,Ak in LDS (16KB); A1,Wv,W2 in VGPRs. LDS 80KB -> 2 blocks/CU.
//   rq (pos for output) reads from the staged LDS tile. Center: 1-ahead
//   reg double-buffer (L2-hot).
// ---------------------------------------------------------------------------

#define NN 16384
#define RING_F 2048   // floats per (wave,slot): nbr 1024 + pos 1024

typedef float f32x4 __attribute__((ext_vector_type(4)));
typedef short s16x8 __attribute__((ext_vector_type(8)));
typedef int   i32x4 __attribute__((ext_vector_type(4)));

__device__ __forceinline__ uint32_t pk2(float a, float b) {
  float2 f; f.x = a; f.y = b;
  __hip_bfloat162 h = __float22bfloat162_rn(f);
  uint32_t u;
  __builtin_memcpy(&u, &h, 4);
  return u;
}

__device__ __forceinline__ f32x4 mma16(i32x4 a, i32x4 b, f32x4 c) {
  return __builtin_amdgcn_mfma_f32_16x16x32_bf16(
      __builtin_bit_cast(s16x8, a), __builtin_bit_cast(s16x8, b), c, 0, 0, 0);
}

__device__ __forceinline__ i32x4 packfrag(f32x4 f0, f32x4 f1) {
  i32x4 r;
  r.x = pk2(f0.x, f0.y); r.y = pk2(f0.z, f0.w);
  r.z = pk2(f1.x, f1.y); r.w = pk2(f1.z, f1.w);
  return r;
}

// ---------------- weight prepass (unchanged layout) ------------------------
__device__ __forceinline__ void wstore(uint16_t* wp, int mat, int j, int k, float v) {
  int ct = j >> 4, jl = j & 15;
  int kt = k >> 5, r = k & 31;
  int kh = r >> 4, rr = r & 15;
  int gg = rr >> 2, e2 = rr & 3;
  int lanei = jl + (gg << 4);
  int e = kh * 4 + e2;
  uint32_t u = __builtin_bit_cast(uint32_t, v);
  u += 0x7fffu + ((u >> 16) & 1u);
  wp[((mat * 8 + kt * 4 + ct) * 64 + lanei) * 8 + e] = (uint16_t)(u >> 16);
}

__global__ void prep_weights(const float* __restrict__ Wq, const float* __restrict__ Wkv,
                             const float* __restrict__ W1, const float* __restrict__ gam,
                             const float* __restrict__ bet, const float* __restrict__ mu,
                             const float* __restrict__ var, const float* __restrict__ W2,
                             uint16_t* __restrict__ wp, float* __restrict__ b1) {
  int j = blockIdx.x * 16 + (threadIdx.x >> 4);
  int q = threadIdx.x & 15;
  float gp = gam[j] * rsqrtf(var[j] + 1e-5f);
  if (q == 0) b1[j] = bet[j] - gp * mu[j];
  for (int k = q * 4; k < q * 4 + 4; ++k) {
    float aq = 0.f, ak = 0.f;
    for (int c = 0; c < 64; ++c) {
      float w1 = W1[j * 64 + c];
      aq += w1 * Wq[c * 64 + k];
      ak += w1 * Wkv[c * 64 + k];
    }
    wstore(wp, 0, j, k, gp * aq);                 // Aq   (LDS)
    wstore(wp, 1, j, k, -gp * ak);                // -Ak  (LDS)
    wstore(wp, 2, j, k, gp * W1[j * 64 + k]);     // A1   (regs)
    wstore(wp, 3, j, k, Wkv[(64 + j) * 64 + k]);  // Wv   (regs)
    wstore(wp, 4, j, k, W2[j * 64 + k]);          // W2   (regs)
  }
}

// ---------------- main fused kernel ----------------------------------------
__device__ __forceinline__ i32x4 bfragld(const uint16_t* wlds, int mat, int kt, int ct, int lane) {
  return *(const i32x4*)(wlds + ((mat * 8 + kt * 4 + ct) * 64 + lane) * 8);
}

__global__ __launch_bounds__(256, 2) void vattn_main(
    const float* __restrict__ center, const float* __restrict__ nbr,
    const float* __restrict__ pos, const uint16_t* __restrict__ wp,
    const float* __restrict__ b1, float* __restrict__ out) {
  __shared__ uint16_t wlds[2 * 4096];        // 16 KB: Aq, -Ak
  __shared__ float ring[4 * 2 * RING_F];     // 64 KB: 4 waves x 2 slots x 8KB
  const int tid = threadIdx.x;
  {
    const i32x4* src = (const i32x4*)wp;     // mats 0,1 = first 1024 i32x4
    i32x4* dst = (i32x4*)wlds;
#pragma unroll
    for (int i = 0; i < 4; ++i) dst[tid + 256 * i] = src[tid + 256 * i];
  }

  const int w = tid >> 6;
  const int lane = tid & 63;
  const int l15 = lane & 15;
  const int g = lane >> 4;

  // A1 / Wv / W2 fragments in registers (one-time global read, L2-hot)
  i32x4 a1f[2][4], wvf[2][4], w2f[2][4];
#pragma unroll
  for (int kt = 0; kt < 2; ++kt)
#pragma unroll
    for (int ct = 0; ct < 4; ++ct) {
      a1f[kt][ct] = *(const i32x4*)(wp + ((16 + kt * 4 + ct) * 64 + lane) * 8);
      wvf[kt][ct] = *(const i32x4*)(wp + ((24 + kt * 4 + ct) * 64 + lane) * 8);
      w2f[kt][ct] = *(const i32x4*)(wp + ((32 + kt * 4 + ct) * 64 + lane) * 8);
    }

  f32x4 binit[4];
#pragma unroll
  for (int ct = 0; ct < 4; ++ct)
#pragma unroll
    for (int r = 0; r < 4; ++r) binit[ct][r] = b1[ct * 16 + 4 * g + r];

  __syncthreads();   // weights staged; ring is per-wave private -> no more barriers

  const int blk = blockIdx.x;
  const int b = blk >> 9;
  const int n0 = (blk & 511) << 5;                  // 32 n per block
  const long nbase = (long)b * NN + n0 + (w << 3);  // 8 n per wave
  float* myring = ring + w * 2 * RING_F;

  // async stage one (nbr,pos) row-pair into a ring slot: 8 x global_load_lds
#define STAGE(SLOT, NR) do {                                                   \
    const float* gn_ = nbr + (long)(NR) * 1024 + lane * 4;                     \
    const float* gp_ = pos + (long)(NR) * 1024 + lane * 4;                     \
    float* l_ = myring + (SLOT) * RING_F;                                      \
    _Pragma("unroll")                                                          \
    for (int c_ = 0; c_ < 4; ++c_) {                                           \
      __builtin_amdgcn_global_load_lds(                                        \
          (const __attribute__((address_space(1))) void*)(gn_ + c_ * 256),     \
          (__attribute__((address_space(3))) void*)(l_ + c_ * 256), 16, 0, 0); \
      __builtin_amdgcn_global_load_lds(                                        \
          (const __attribute__((address_space(1))) void*)(gp_ + c_ * 256),     \
          (__attribute__((address_space(3))) void*)(l_ + 1024 + c_ * 256), 16, 0, 0); \
    }                                                                          \
  } while (0)

  f32x4 cc[2][4];
#define CCLOAD(BUF, NR) do {                                                   \
    const float* crp_ = center + (long)(NR) * 64 + g * 4;                      \
    cc[BUF][0] = *(const f32x4*)crp_;        cc[BUF][1] = *(const f32x4*)(crp_ + 16); \
    cc[BUF][2] = *(const f32x4*)(crp_ + 32); cc[BUF][3] = *(const f32x4*)(crp_ + 48); \
  } while (0)

  // prologue: slot0(n0), center(n0), slot1(n1) -> 20 vmem ops outstanding
  STAGE(0, nbase);
  CCLOAD(0, nbase);
  STAGE(1, nbase + 1);

#pragma unroll
  for (int rt = 0; rt < 8; ++rt) {
    const int slot = rt & 1;
    // wait current slot (+ its center) done; keep the other slot's 8 in flight
    if (rt == 7) asm volatile("s_waitcnt vmcnt(0)" ::: "memory");
    else         asm volatile("s_waitcnt vmcnt(8)" ::: "memory");

    // ---- read phase: ring slot -> registers (raw f32) ----
    const float* dn = myring + slot * RING_F;        // nbr tile [16m][64ch]
    const float* dp = dn + 1024;                     // pos tile
    const float* nb_ = dn + l15 * 64 + g * 4;
    f32x4 rn0 = *(const f32x4*)nb_,        rn1 = *(const f32x4*)(nb_ + 16);
    f32x4 rn2 = *(const f32x4*)(nb_ + 32), rn3 = *(const f32x4*)(nb_ + 48);
    const float* pb_ = dp + l15 * 64 + g * 4;
    f32x4 rp0 = *(const f32x4*)pb_,        rp1 = *(const f32x4*)(pb_ + 16);
    f32x4 rp2 = *(const f32x4*)(pb_ + 32), rp3 = *(const f32x4*)(pb_ + 48);
    f32x4 rq[4];   // pos in C/D layout for V accumulator init
#pragma unroll
    for (int ct = 0; ct < 4; ++ct)
#pragma unroll
      for (int r = 0; r < 4; ++r)
        rq[ct][r] = dp[(4 * g + r) * 64 + ct * 16 + l15];
    // reads must complete before this slot is overwritten below
    asm volatile("s_waitcnt lgkmcnt(0)" ::: "memory");
    __builtin_amdgcn_sched_barrier(0);

    // ---- issue phase: next center, then restage this slot with n+2 ----
    if (rt + 1 < 8) CCLOAD((rt + 1) & 1, nbase + rt + 1);
    if (rt + 2 < 8) STAGE(slot, nbase + rt + 2);

    // ---- compute phase ----
    i32x4 na0 = packfrag(rn0, rn1), na1 = packfrag(rn2, rn3);
    i32x4 pa0 = packfrag(rp0, rp1), pa1 = packfrag(rp2, rp3);
    i32x4 ca0 = packfrag(cc[slot][0], cc[slot][1]);
    i32x4 ca1 = packfrag(cc[slot][2], cc[slot][3]);

    // GEMM1 (transposed): h^T[ch][m]. Aq/Ak from LDS, A1 from regs. 24 MFMAs.
    f32x4 h[4];
#pragma unroll
    for (int ct = 0; ct < 4; ++ct) {
      h[ct] = binit[ct];
      h[ct] = mma16(bfragld(wlds, 0, 0, ct, lane), ca0, h[ct]);  // Aq · center
      h[ct] = mma16(bfragld(wlds, 0, 1, ct, lane), ca1, h[ct]);
      h[ct] = mma16(bfragld(wlds, 1, 0, ct, lane), na0, h[ct]);  // -Ak · nbr
      h[ct] = mma16(bfragld(wlds, 1, 1, ct, lane), na1, h[ct]);
      h[ct] = mma16(a1f[0][ct], pa0, h[ct]);                     // A1 · pos
      h[ct] = mma16(a1f[1][ct], pa1, h[ct]);
    }

    // V GEMM: vv[m][cv] = pos(C-init) + nbr@Wv^T. 8 MFMAs.
    f32x4 vv[4];
#pragma unroll
    for (int ct = 0; ct < 4; ++ct) {
      vv[ct] = rq[ct];
      vv[ct] = mma16(na0, wvf[0][ct], vv[ct]);
      vv[ct] = mma16(na1, wvf[1][ct], vv[ct]);
    }

    // relu + repack: h^T C/D layout IS the A-frag layout for GEMM2
    i32x4 ha0, ha1;
    {
      f32x4 r0, r1, r2, r3;
#pragma unroll
      for (int r = 0; r < 4; ++r) {
        r0[r] = fmaxf(h[0][r], 0.f); r1[r] = fmaxf(h[1][r], 0.f);
        r2[r] = fmaxf(h[2][r], 0.f); r3[r] = fmaxf(h[3][r], 0.f);
      }
      ha0 = packfrag(r0, r1);
      ha1 = packfrag(r2, r3);
    }

    // GEMM2: a2[m][c2] = relu(h) @ W2^T (regs). 8 MFMAs.
    f32x4 a2[4];
#pragma unroll
    for (int ct = 0; ct < 4; ++ct) {
      a2[ct] = (f32x4){0.f, 0.f, 0.f, 0.f};
      a2[ct] = mma16(ha0, w2f[0][ct], a2[ct]);
      a2[ct] = mma16(ha1, w2f[1][ct], a2[ct]);
    }

    // softmax over m + weighted sum — all in-register
    const long nrow = nbase + rt;
    float ov[4];
#pragma unroll
    for (int ct = 0; ct < 4; ++ct) {
      f32x4 s = a2[ct];
      float mx = fmaxf(fmaxf(s.x, s.y), fmaxf(s.z, s.w));
      mx = fmaxf(mx, __shfl_xor(mx, 16, 64));
      mx = fmaxf(mx, __shfl_xor(mx, 32, 64));
      float e0 = __expf(s.x - mx), e1 = __expf(s.y - mx);
      float e2 = __expf(s.z - mx), e3 = __expf(s.w - mx);
      float sm = e0 + e1 + e2 + e3;
      sm += __shfl_xor(sm, 16, 64);
      sm += __shfl_xor(sm, 32, 64);
      float ps = e0 * vv[ct].x + e1 * vv[ct].y + e2 * vv[ct].z + e3 * vv[ct].w;
      ps += __shfl_xor(ps, 16, 64);
      ps += __shfl_xor(ps, 32, 64);
      ov[ct] = ps * __builtin_amdgcn_rcpf(sm);
    }
    float val = (g == 0) ? ov[0] : (g == 1) ? ov[1] : (g == 2) ? ov[2] : ov[3];
    out[nrow * 64 + lane] = val;
  }
#undef STAGE
#undef CCLOAD
}

// ---------------------------------------------------------------------------
extern "C" void kernel_launch(void* const* d_in, const int* in_sizes, int n_in,
                              void* d_out, int out_size, void* d_ws, size_t ws_size,
                              hipStream_t stream) {
  const float* center = (const float*)d_in[0];
  const float* nbr    = (const float*)d_in[1];
  const float* pos    = (const float*)d_in[2];
  const float* Wq     = (const float*)d_in[3];
  const float* Wkv    = (const float*)d_in[4];
  const float* W1     = (const float*)d_in[5];
  const float* gam    = (const float*)d_in[6];
  const float* bet    = (const float*)d_in[7];
  const float* mu     = (const float*)d_in[8];
  const float* var    = (const float*)d_in[9];
  const float* W2     = (const float*)d_in[10];
  uint16_t* wp = (uint16_t*)d_ws;
  float* b1 = (float*)((char*)d_ws + 5 * 4096 * 2);
  prep_weights<<<4, 256, 0, stream>>>(Wq, Wkv, W1, gam, bet, mu, var, W2, wp, b1);
  vattn_main<<<1024, 256, 0, stream>>>(center, nbr, pos, wp, b1, (float*)d_out);
}